// Round 1
// baseline (44.208 us; speedup 1.0000x reference)
//
#include <hip/hip_runtime.h>
#include <math.h>

// Problem constants (match reference setup_inputs)
#define BB 128
#define PP 256
#define CC 1000

// ws layout (floats): [0:256) wsq[p], [256:384) g_sqrtsum[b], [384:512) g_frosum[b]

__global__ __launch_bounds__(256) void k_prep(const float* __restrict__ W,
                                              float* __restrict__ ws) {
    int t = threadIdx.x;  // 256 threads, t == p
    if (t < BB) {
        ws[256 + t] = 0.f;
        ws[384 + t] = 0.f;
    }
    float acc = 0.f;
#pragma unroll 8
    for (int c = 0; c < CC; ++c) {
        float w = W[c * PP + t];  // coalesced across t
        acc += w * w;
    }
    ws[t] = acc;
}

__global__ __launch_bounds__(256) void k_main(const float* __restrict__ W,
                                              const float* __restrict__ S,
                                              float* __restrict__ ws) {
    __shared__ float s2s[16][260];     // pad 256->260: row starts 4 banks apart
    __shared__ float red_sq[16][17];
    __shared__ float red_fr[16][17];

    int t = threadIdx.x;
    int b0 = blockIdx.x * 16;
    int c0 = blockIdx.y * 16;

    // stage s^2 tile (16 b-rows x 256 p), coalesced
#pragma unroll
    for (int i = 0; i < 16; ++i) {
        int idx = t + 256 * i;
        int row = idx >> 8, col = idx & 255;
        float s = S[(b0 + row) * PP + col];
        s2s[row][col] = s * s;
    }
    __syncthreads();

    int bl = t & 15;   // b within tile
    int cl = t >> 4;   // c within tile
    int c = c0 + cl;

    float acc = 0.f;
    if (c < CC) {
        const float4* w4 = (const float4*)(W + c * PP);
#pragma unroll 4
        for (int p = 0; p < 64; ++p) {
            float4 w = w4[p];  // 16 lanes share c -> broadcast
            float4 s2 = *(const float4*)&s2s[bl][p * 4];
            acc += s2.x * (w.x * w.x);
            acc += s2.y * (w.y * w.y);
            acc += s2.z * (w.z * w.z);
            acc += s2.w * (w.w * w.w);
        }
    }
    // acc = M[b,c] = sum_p s2*w2   (0 for padded c)
    float sq = (c < CC) ? sqrtf(acc) : 0.f;

    red_sq[cl][bl] = sq;
    red_fr[cl][bl] = acc;
    __syncthreads();

    if (t < 16) {  // t == bl; reduce over the 16 c-lanes
        float ssum = 0.f, fsum = 0.f;
#pragma unroll
        for (int j = 0; j < 16; ++j) {
            ssum += red_sq[j][t];
            fsum += red_fr[j][t];
        }
        atomicAdd(&ws[256 + b0 + t], ssum);
        atomicAdd(&ws[384 + b0 + t], fsum);
    }
}

__global__ __launch_bounds__(128) void k_fin(const float* __restrict__ S,
                                             const float* __restrict__ ws,
                                             float* __restrict__ out) {
    int b = threadIdx.x;  // 128 threads, one per batch row
    float tb = 0.f;
#pragma unroll 8
    for (int p = 0; p < PP; ++p) {
        float s = S[b * PP + p];
        tb += fabsf(s) * sqrtf(ws[p]);
    }
    float ta = ws[256 + b];
    float fsq = ws[384 + b];
    float inv_scale = 1.0f / sqrtf((float)(PP * CC));
    float sparsity = (ta * ta + tb * tb) / (fsq + 1e-20f);
    sparsity *= inv_scale;
    sparsity += sqrtf(fsq);

    __shared__ float red[BB];
    red[b] = sparsity;
    __syncthreads();
    if (b == 0) {
        float sum = 0.f;
        for (int i = 0; i < BB; ++i) sum += red[i];
        out[0] = sum / (float)BB;
    }
}

extern "C" void kernel_launch(void* const* d_in, const int* in_sizes, int n_in,
                              void* d_out, int out_size, void* d_ws, size_t ws_size,
                              hipStream_t stream) {
    const float* W = (const float*)d_in[0];  // [C=1000, P=256]
    const float* S = (const float*)d_in[1];  // [B=128, P=256]
    float* out = (float*)d_out;              // scalar
    float* ws = (float*)d_ws;                // >= 512 floats

    hipLaunchKernelGGL(k_prep, dim3(1), dim3(256), 0, stream, W, ws);
    hipLaunchKernelGGL(k_main, dim3(8, 63), dim3(256), 0, stream, W, S, ws);
    hipLaunchKernelGGL(k_fin, dim3(1), dim3(128), 0, stream, S, ws, out);
}

// Round 2
// 23.287 us; speedup vs baseline: 1.8984x; 1.8984x over previous
//
#include <hip/hip_runtime.h>
#include <math.h>

// Problem constants (match reference setup_inputs)
#define BB 128
#define PP 256
#define CC 1000

// ws layout (floats): [0:256) wsq[p], [256:384) sqrtsum[b], [384:512) frosum[b]
// All three regions are zeroed by hipMemsetAsync before the fused kernel.

#define NMAIN 504   // 8 b-tiles x 63 c-tiles
#define NPREP 32    // 32 blocks x ~32 c-rows for wsq column sums

__global__ __launch_bounds__(256) void k_fused(const float* __restrict__ W,
                                               const float* __restrict__ S,
                                               float* __restrict__ ws) {
    int bid = blockIdx.x;
    int t = threadIdx.x;

    if (bid >= NMAIN) {
        // ---- wsq part: partial column sums of W^2, 32 blocks x 32 c-rows ----
        int k = bid - NMAIN;          // 0..31
        int c_lo = k * 32;
        int c_hi = min(CC, c_lo + 32);
        float acc = 0.f;
        for (int c = c_lo; c < c_hi; ++c) {
            float w = W[c * PP + t];  // coalesced across t (= p)
            acc += w * w;
        }
        atomicAdd(&ws[t], acc);
        return;
    }

    // ---- main part: M[b,c] = sum_p s^2 w^2 over a 16b x 16c tile ----
    __shared__ float s2s[16][260];     // pad 256->260
    __shared__ float red_sq[16][17];
    __shared__ float red_fr[16][17];

    int b0 = (bid & 7) * 16;
    int c0 = (bid >> 3) * 16;

#pragma unroll
    for (int i = 0; i < 16; ++i) {
        int idx = t + 256 * i;
        int row = idx >> 8, col = idx & 255;
        float s = S[(b0 + row) * PP + col];
        s2s[row][col] = s * s;
    }
    __syncthreads();

    int bl = t & 15;   // b within tile
    int cl = t >> 4;   // c within tile
    int c = c0 + cl;

    float acc = 0.f;
    if (c < CC) {
        const float4* w4 = (const float4*)(W + c * PP);
#pragma unroll 4
        for (int p = 0; p < 64; ++p) {
            float4 w = w4[p];  // 16 lanes share c -> broadcast
            float4 s2 = *(const float4*)&s2s[bl][p * 4];
            acc += s2.x * (w.x * w.x);
            acc += s2.y * (w.y * w.y);
            acc += s2.z * (w.z * w.z);
            acc += s2.w * (w.w * w.w);
        }
    }
    float sq = (c < CC) ? sqrtf(acc) : 0.f;

    red_sq[cl][bl] = sq;
    red_fr[cl][bl] = acc;
    __syncthreads();

    if (t < 16) {  // t == bl; reduce over the 16 c-lanes
        float ssum = 0.f, fsum = 0.f;
#pragma unroll
        for (int j = 0; j < 16; ++j) {
            ssum += red_sq[j][t];
            fsum += red_fr[j][t];
        }
        atomicAdd(&ws[256 + b0 + t], ssum);
        atomicAdd(&ws[384 + b0 + t], fsum);
    }
}

__global__ __launch_bounds__(256) void k_fin(const float* __restrict__ S,
                                             const float* __restrict__ ws,
                                             float* __restrict__ out) {
    int t = threadIdx.x;
    __shared__ float sw[PP];
    __shared__ float red[BB];

    sw[t] = sqrtf(ws[t]);   // 256 threads, one sqrt each
    __syncthreads();

    if (t < BB) {
        int b = t;
        float tb = 0.f;
        const float4* s4 = (const float4*)(S + b * PP);
#pragma unroll 8
        for (int p = 0; p < PP / 4; ++p) {
            float4 s = s4[p];
            tb += fabsf(s.x) * sw[p * 4 + 0];
            tb += fabsf(s.y) * sw[p * 4 + 1];
            tb += fabsf(s.z) * sw[p * 4 + 2];
            tb += fabsf(s.w) * sw[p * 4 + 3];
        }
        float ta = ws[256 + b];
        float fsq = ws[384 + b];
        float inv_scale = 1.0f / sqrtf((float)(PP * CC));
        float sparsity = (ta * ta + tb * tb) / (fsq + 1e-20f);
        sparsity *= inv_scale;
        sparsity += sqrtf(fsq);
        red[b] = sparsity;
    }
    __syncthreads();
    if (t == 0) {
        float sum = 0.f;
        for (int i = 0; i < BB; ++i) sum += red[i];
        out[0] = sum / (float)BB;
    }
}

extern "C" void kernel_launch(void* const* d_in, const int* in_sizes, int n_in,
                              void* d_out, int out_size, void* d_ws, size_t ws_size,
                              hipStream_t stream) {
    const float* W = (const float*)d_in[0];  // [C=1000, P=256]
    const float* S = (const float*)d_in[1];  // [B=128, P=256]
    float* out = (float*)d_out;              // scalar
    float* ws = (float*)d_ws;                // >= 512 floats

    hipMemsetAsync(ws, 0, 512 * sizeof(float), stream);
    hipLaunchKernelGGL(k_fused, dim3(NMAIN + NPREP), dim3(256), 0, stream, W, S, ws);
    hipLaunchKernelGGL(k_fin, dim3(1), dim3(256), 0, stream, S, ws, out);
}

// Round 3
// 20.281 us; speedup vs baseline: 2.1798x; 1.1482x over previous
//
#include <hip/hip_runtime.h>
#include <math.h>

// Problem constants (match reference setup_inputs)
#define BB 128
#define PP 256
#define CC 1000

#define NMAIN 504   // 8 b-tiles x 63 c-tiles
#define NPREP 32    // 32 blocks of ~32 c-rows each for wsq partial column sums
#define NCT   63    // c-tiles

// ws layout (floats) — every slot has exactly ONE writer, no zeroing needed:
//   [0      : 8192)  part_w [k][p]   k=0..31, p=0..255   (wsq partials)
//   [8192   : 16256) part_sq[ct][b]  ct=0..62, b=0..127  (sqrt-of-M row partials)
//   [16256  : 24320) part_fr[ct][b]                       (M row partials)
#define OFF_W  0
#define OFF_SQ 8192
#define OFF_FR 16256

__global__ __launch_bounds__(256) void k1(const float* __restrict__ W,
                                          const float* __restrict__ S,
                                          float* __restrict__ ws) {
    int bid = blockIdx.x;
    int t = threadIdx.x;

    if (bid >= NMAIN) {
        // ---- wsq partials: 32 blocks x up to 32 c-rows ----
        int k = bid - NMAIN;          // 0..31
        int c_lo = k * 32;
        int c_hi = min(CC, c_lo + 32);
        float acc = 0.f;
        for (int c = c_lo; c < c_hi; ++c) {
            float w = W[c * PP + t];  // coalesced across t (= p)
            acc += w * w;
        }
        ws[OFF_W + k * 256 + t] = acc;   // plain store, unique slot
        return;
    }

    // ---- main: M[b,c] = sum_p s^2 w^2 over a 16b x 16c tile ----
    __shared__ float s2s[16][260];     // pad 256->260
    __shared__ float red_sq[16][17];
    __shared__ float red_fr[16][17];

    int bt = bid & 7;
    int ct = bid >> 3;                 // 0..62
    int b0 = bt * 16;
    int c0 = ct * 16;

#pragma unroll
    for (int i = 0; i < 16; ++i) {
        int idx = t + 256 * i;
        int row = idx >> 8, col = idx & 255;
        float s = S[(b0 + row) * PP + col];
        s2s[row][col] = s * s;
    }
    __syncthreads();

    int bl = t & 15;   // b within tile
    int cl = t >> 4;   // c within tile
    int c = c0 + cl;

    float acc = 0.f;
    if (c < CC) {
        const float4* w4 = (const float4*)(W + c * PP);
#pragma unroll 4
        for (int p = 0; p < 64; ++p) {
            float4 w = w4[p];  // 16 lanes share c -> broadcast
            float4 s2 = *(const float4*)&s2s[bl][p * 4];
            acc += s2.x * (w.x * w.x);
            acc += s2.y * (w.y * w.y);
            acc += s2.z * (w.z * w.z);
            acc += s2.w * (w.w * w.w);
        }
    }
    float sq = (c < CC) ? sqrtf(acc) : 0.f;

    red_sq[cl][bl] = sq;
    red_fr[cl][bl] = acc;
    __syncthreads();

    if (t < 16) {  // t == local b; reduce over the 16 c-lanes
        float ssum = 0.f, fsum = 0.f;
#pragma unroll
        for (int j = 0; j < 16; ++j) {
            ssum += red_sq[j][t];
            fsum += red_fr[j][t];
        }
        ws[OFF_SQ + ct * BB + b0 + t] = ssum;   // unique slot
        ws[OFF_FR + ct * BB + b0 + t] = fsum;   // unique slot
    }
}

__global__ __launch_bounds__(256) void k2(const float* __restrict__ S,
                                          const float* __restrict__ ws,
                                          float* __restrict__ out) {
    int t = threadIdx.x;
    __shared__ float sw[PP];
    __shared__ float red[BB];

    // 1) reduce wsq partials (coalesced over t for each k), then sqrt
    float a = 0.f;
#pragma unroll 8
    for (int k = 0; k < NPREP; ++k) a += ws[OFF_W + k * 256 + t];
    sw[t] = sqrtf(a);
    __syncthreads();

    if (t < BB) {
        int b = t;
        // 2) reduce per-b partials over 63 c-tiles (coalesced over b)
        float ta = 0.f, fsq = 0.f;
        for (int ct = 0; ct < NCT; ++ct) {
            ta  += ws[OFF_SQ + ct * BB + b];
            fsq += ws[OFF_FR + ct * BB + b];
        }
        // 3) term_b from S row b
        float tb = 0.f;
        const float4* s4 = (const float4*)(S + b * PP);
#pragma unroll 8
        for (int p = 0; p < PP / 4; ++p) {
            float4 s = s4[p];
            tb += fabsf(s.x) * sw[p * 4 + 0];
            tb += fabsf(s.y) * sw[p * 4 + 1];
            tb += fabsf(s.z) * sw[p * 4 + 2];
            tb += fabsf(s.w) * sw[p * 4 + 3];
        }
        float inv_scale = 1.0f / sqrtf((float)(PP * CC));
        float sparsity = (ta * ta + tb * tb) / (fsq + 1e-20f);
        sparsity *= inv_scale;
        sparsity += sqrtf(fsq);
        red[b] = sparsity;
    }
    __syncthreads();
    if (t == 0) {
        float sum = 0.f;
        for (int i = 0; i < BB; ++i) sum += red[i];
        out[0] = sum / (float)BB;
    }
}

extern "C" void kernel_launch(void* const* d_in, const int* in_sizes, int n_in,
                              void* d_out, int out_size, void* d_ws, size_t ws_size,
                              hipStream_t stream) {
    const float* W = (const float*)d_in[0];  // [C=1000, P=256]
    const float* S = (const float*)d_in[1];  // [B=128, P=256]
    float* out = (float*)d_out;              // scalar
    float* ws = (float*)d_ws;                // >= 24320 floats (~95 KB)

    hipLaunchKernelGGL(k1, dim3(NMAIN + NPREP), dim3(256), 0, stream, W, S, ws);
    hipLaunchKernelGGL(k2, dim3(1), dim3(256), 0, stream, S, ws, out);
}